// Round 7
// baseline (223.665 us; speedup 1.0000x reference)
//
#include <hip/hip_runtime.h>
#include <stdint.h>

// GQA fused forward: B=2, S=1024, HIDDEN=2048, H=32, G=8, D=64, causal.
// I/O float32; internal bf16 MFMA. Mask input ignored (causal from indices).
//
// Pipeline (round 7: weight f32->bf16 conversion fused into GEMM B-staging):
//   0) cvt:       f32 -> bf16 copy of x ONLY (weights consumed f32 by GEMMs)
//   1) qkv_gemm:  128x64 tiles, 768 blocks (3/CU), full K=2048, fused bias+
//                 scatter. B staged from f32 W via reg-cvt (issue-early).
//                 XCD-rect swizzle: each XCD owns 8m x 12ty.
//   2) attn:      S^T-form flash attention, PAIRED q-tiles {x,15-x} per block,
//                 Q direct from global, double-buffered K/V staging + setprio.
//   3) out_gemm:  128x64 tiles, 512 blocks (2/CU), full K, fused bias -> f32.
//                 B staged from f32 Wo via reg-cvt. XCD-rect 8m x 8ty.
//
// NOTE (round-1 post-mortem): device-scope __threadfence() per block for a
// last-block split-K fixup compiles to buffer_wbl2/buffer_inv (full L2
// writeback+invalidate per XCD). 384 of those took qkv_gemm 38us -> 150us.
// Never fuse cross-block reductions via atomics+fences here.
//
// NOTE (round-4 post-mortem): un-pairing attn into 1024 one-q-tile blocks
// (4/CU) REGRESSED 35->50us (staging-queue contention + tail decay). Paired
// uniform blocks at 2/CU are faster. Do not un-pair.
//
// NOTE (round-6 post-mortem): XCD-rect swizzle for the GEMMs was NEUTRAL
// (205->203, noise): the GEMMs are staging/issue-latency-bound, not HBM-BW
// bound -- redundant W reads were hidden by L2/latency. Swizzle kept
// (harmless). Corollary: GEMM-phase wins must shorten the TIMELINE, which is
// why this round deletes the weight-conversion pass instead (weights have
// zero reuse across the pipeline -- their cvt round trip was pure timeline).

typedef __bf16 bf16_8 __attribute__((ext_vector_type(8)));
typedef float f32x4 __attribute__((ext_vector_type(4)));

__device__ __forceinline__ unsigned short f2bf(float f) {
  union { float f; unsigned int i; } c; c.f = f;
  unsigned int u = c.i;
  return (unsigned short)((u + 0x7fffu + ((u >> 16) & 1u)) >> 16);
}

__device__ __forceinline__ void gl2lds16(const void* g, void* l) {
  __builtin_amdgcn_global_load_lds(
      (const __attribute__((address_space(1))) void*)g,
      (__attribute__((address_space(3))) void*)l, 16, 0, 0);
}

// Stage ROWS x 64 bf16 tile (leading dim ldg) into LDS; per-row XOR swizzle of
// 8-elem groups: LDS[r][lg] = G[r][lg ^ (r&7)]. 256 threads.
template <int ROWS>
__device__ __forceinline__ void stage_tile(const unsigned short* g, int ldg,
                                           unsigned short* lds, int tid) {
#pragma unroll
  for (int i = 0; i < ROWS * 8 / 256; ++i) {
    int c = tid + i * 256;
    int r = c >> 3;
    int grp = (c & 7) ^ (r & 7);
    gl2lds16(g + (size_t)r * ldg + grp * 8, lds + c * 8);
  }
}

// --- B-tile staging from f32 weights (64x64), reg-cvt, same swizzle -------
// Read linear (coalesced 32B/lane), write LDS[r][lg^(r&7)] -- the XOR is an
// involution, so the resulting LDS layout is identical to stage_tile's
// (which reads G[r][lg^(r&7)] and writes linear). Values use the same f2bf.
__device__ __forceinline__ void stageB_load(const float* g, int ldg, int tid,
                                            float4 v[4]) {
#pragma unroll
  for (int i = 0; i < 2; ++i) {
    int c = tid + i * 256;
    int r = c >> 3, lg = c & 7;
    const float* src = g + (size_t)r * ldg + lg * 8;
    v[2 * i]     = *(const float4*)src;
    v[2 * i + 1] = *(const float4*)(src + 4);
  }
}
__device__ __forceinline__ void stageB_write(unsigned short* lds, int tid,
                                             const float4 v[4]) {
#pragma unroll
  for (int i = 0; i < 2; ++i) {
    int c = tid + i * 256;
    int r = c >> 3, lg = c & 7;
    unsigned int o0 = f2bf(v[2 * i].x)     | ((unsigned int)f2bf(v[2 * i].y) << 16);
    unsigned int o1 = f2bf(v[2 * i].z)     | ((unsigned int)f2bf(v[2 * i].w) << 16);
    unsigned int o2 = f2bf(v[2 * i + 1].x) | ((unsigned int)f2bf(v[2 * i + 1].y) << 16);
    unsigned int o3 = f2bf(v[2 * i + 1].z) | ((unsigned int)f2bf(v[2 * i + 1].w) << 16);
    int grp = lg ^ (r & 7);
    *(uint4*)(lds + r * 64 + grp * 8) = make_uint4(o0, o1, o2, o3);
  }
}

// Core 128x64 GEMM tile: Y = X[128,K](bf16) @ W[64,K](f32)^T.
// 4 waves, each owns a 32x64 output stripe: acc[2][4] of 16x16 frags.
// B f32 loads are issued BEFORE the LDS-reuse barrier (they touch no LDS),
// hiding their latency under the previous tile's compute + drain (T14).
__device__ __forceinline__ void gemm_core_n64(const unsigned short* Xt,
                                              const float* Wt,
                                              int kiter, int ld, int tid,
                                              unsigned short* sA,
                                              unsigned short* sB,
                                              f32x4 acc[2][4]) {
  const int wave = tid >> 6, lane = tid & 63;
  const int wm = wave << 5;
  const int lrow = lane & 15, quad = lane >> 4;
  for (int k0 = 0; k0 < kiter; k0 += 64) {
    float4 bv[4];
    stageB_load(Wt + k0, ld, tid, bv);      // issue early: no LDS touched
    __syncthreads();                        // prev-tile compute done
    stage_tile<128>(Xt + k0, ld, sA, tid);  // A via global_load_lds
    stageB_write(sB, tid, bv);              // cvt + swizzled ds_write
    __syncthreads();                        // staging complete
#pragma unroll
    for (int ks = 0; ks < 2; ++ks) {
      bf16_8 af[2], bw[4];
#pragma unroll
      for (int i = 0; i < 2; ++i) {
        int ra = wm + i * 16 + lrow;
        af[i] = *(const bf16_8*)(sA + ra * 64 + (((ks << 2) + quad) ^ (ra & 7)) * 8);
      }
#pragma unroll
      for (int j = 0; j < 4; ++j) {
        int rb = j * 16 + lrow;
        bw[j] = *(const bf16_8*)(sB + rb * 64 + (((ks << 2) + quad) ^ (rb & 7)) * 8);
      }
#pragma unroll
      for (int i = 0; i < 2; ++i)
#pragma unroll
        for (int j = 0; j < 4; ++j)
          acc[i][j] = __builtin_amdgcn_mfma_f32_16x16x32_bf16(af[i], bw[j],
                                                              acc[i][j], 0, 0, 0);
    }
  }
}

// ---------------- kernel 0: f32 -> bf16 conversion (x only) ----------------
__global__ void __launch_bounds__(256)
cvt_kernel(const float* __restrict__ src, unsigned short* __restrict__ dst) {
  int idx = (blockIdx.x * 256 + threadIdx.x) * 4;
  float4 v = *(const float4*)(src + idx);
  ushort4 o;
  o.x = f2bf(v.x); o.y = f2bf(v.y); o.z = f2bf(v.z); o.w = f2bf(v.w);
  *(ushort4*)(dst + idx) = o;
}

// ---------------- kernel 1: QKV projection, fused bias+scatter -------------
// 1D grid (768). XCD-rect swizzle: xcd=bid&7 owns an 8m x 12ty rectangle.
// ty 0..31 -> Q head ty; 32..39 -> K group; 40..47 -> V group (n = ty*64).
// Weights consumed directly as f32 (reg-cvt in B staging).
__global__ void __launch_bounds__(256)
qkv_gemm(const unsigned short* __restrict__ X,
         const float* __restrict__ Wq,
         const float* __restrict__ Wk,
         const float* __restrict__ Wv,
         const float* __restrict__ bq, const float* __restrict__ bk,
         const float* __restrict__ bv,
         unsigned short* __restrict__ qws, unsigned short* __restrict__ kws,
         unsigned short* __restrict__ vws) {
  __shared__ unsigned short sA[128 * 64], sB[64 * 64];
  const int tid = threadIdx.x;
  const int bid = blockIdx.x;
  const int xcd = bid & 7, idx = bid >> 3;        // 96 blocks per XCD
  const int mt  = ((xcd & 1) << 3) + idx / 12;    // [0,16)
  const int ty  = (xcd >> 1) * 12 + idx % 12;     // [0,48)
  const int tileM = mt * 128;
  const float* W;
  const float* bias;
  if (ty < 32)      { W = Wq + (size_t)ty * 64 * 2048;        bias = bq + ty * 64; }
  else if (ty < 40) { W = Wk + (size_t)(ty - 32) * 64 * 2048; bias = bk + (ty - 32) * 64; }
  else              { W = Wv + (size_t)(ty - 40) * 64 * 2048; bias = bv + (ty - 40) * 64; }

  f32x4 acc[2][4] = {};
  gemm_core_n64(X + (size_t)tileM * 2048, W, 2048, 2048, tid, sA, sB, acc);

  const int wave = tid >> 6, lane = tid & 63;
  const int wm = wave << 5;
  const int lrow = lane & 15, quad = lane >> 4;

#pragma unroll
  for (int j = 0; j < 4; ++j) {
    const int dloc = j * 16 + lrow;          // 0..63: dim within this 64-slice
    const float bj = bias[dloc];
#pragma unroll
    for (int i = 0; i < 2; ++i) {
      const int mbase = tileM + wm + i * 16 + quad * 4;
      const int b = mbase >> 10;
      const int s = mbase & 1023;            // s, s+1, s+2, s+3 for r=0..3
      if (ty < 32) {
        unsigned short* p = qws + ((((size_t)b * 32 + ty) << 10) + s) * 64 + dloc;
#pragma unroll
        for (int r = 0; r < 4; ++r) p[r * 64] = f2bf(acc[i][j][r] + bj);
      } else if (ty < 40) {
        unsigned short* p = kws + ((((size_t)b * 8 + (ty - 32)) << 10) + s) * 64 + dloc;
#pragma unroll
        for (int r = 0; r < 4; ++r) p[r * 64] = f2bf(acc[i][j][r] + bj);
      } else {
        // vws[b, g, d, s] (transposed): r=0..3 are consecutive s -> pack 8B
        unsigned short* p = vws + ((((size_t)b * 8 + (ty - 40)) * 64 + dloc) << 10) + s;
        uint2 pk;
        pk.x = f2bf(acc[i][j][0] + bj) | ((unsigned int)f2bf(acc[i][j][1] + bj) << 16);
        pk.y = f2bf(acc[i][j][2] + bj) | ((unsigned int)f2bf(acc[i][j][3] + bj) << 16);
        *(uint2*)p = pk;
      }
    }
  }
}

// ---------------- kernel 2: causal flash attention (S^T form) ----------------
// grid (8, 32, 2): (pair, head, batch). Block handles q-tiles {x, 15-x}:
// uniform 17 kc-iters per block, XCD-balanced by construction. Q fragments
// loaded direct from global (no sQ; LDS 40KB). Double-buffered K/V staging:
// 1 barrier/iter, next tile staged before compute. setprio around MFMA.
__global__ void __launch_bounds__(256)
attn_kernel(const unsigned short* __restrict__ Qw, const unsigned short* __restrict__ Kw,
            const unsigned short* __restrict__ Vt, unsigned short* __restrict__ Ow) {
  __shared__ unsigned short sK[2][64 * 64], sVt[2][64 * 64], sPt[64 * 64];
  const int tid = threadIdx.x;
  const int pair = blockIdx.x, h = blockIdx.y, b = blockIdx.z;
  const int g = h >> 2;
  const unsigned short* Kb = Kw + (((size_t)b * 8 + g) << 16);  // [s][d]
  const unsigned short* Vb = Vt + (((size_t)b * 8 + g) << 16);  // [d][s], ld=1024
  const int wave = tid >> 6, lane = tid & 63;
  const int lrow = lane & 15, quad = lane >> 4;
  const int qloc = wave * 16 + lrow;
  const float C = 0.18033688f;  // 0.125 * log2(e)

#pragma unroll 1
  for (int t = 0; t < 2; ++t) {
    const int qt = t ? (15 - pair) : pair;
    __syncthreads();  // protect sK/sVt/sPt reuse across t iterations

    // Q fragments straight from global: Q[b,h, qt*64+qloc, (kh*4+quad)*8 ..+8]
    const unsigned short* Qrow =
        Qw + ((((size_t)b * 32 + h) << 10) + qt * 64 + qloc) * 64;
    bf16_8 qf[2];
#pragma unroll
    for (int kh = 0; kh < 2; ++kh)
      qf[kh] = *(const bf16_8*)(Qrow + ((kh << 2) + quad) * 8);

    stage_tile<64>(Kb, 64, sK[0], tid);
    stage_tile<64>(Vb, 1024, sVt[0], tid);
    __syncthreads();

    float m_i = -INFINITY, l_i = 0.f;
    f32x4 o[4] = {};
    const int q_g = qt * 64 + qloc;
    int cur = 0;

#pragma unroll 1
    for (int kc = 0; kc <= qt; ++kc) {
      if (kc) __syncthreads();  // staging of buf[cur] done; buf[cur^1] free
      if (kc < qt) {
        // issue next-tile staging BEFORE compute: latency hides under MFMA
        stage_tile<64>(Kb + (size_t)(kc + 1) * 64 * 64, 64, sK[cur ^ 1], tid);
        stage_tile<64>(Vb + (kc + 1) * 64, 1024, sVt[cur ^ 1], tid);
      }
      const unsigned short* sKc = sK[cur];
      const unsigned short* sVc = sVt[cur];

      f32x4 sc[4] = {};
      __builtin_amdgcn_s_setprio(1);
#pragma unroll
      for (int kh = 0; kh < 2; ++kh)
#pragma unroll
        for (int mt = 0; mt < 4; ++mt) {
          int kv = mt * 16 + lrow;
          bf16_8 kf = *(const bf16_8*)(sKc + kv * 64 + (((kh << 2) + quad) ^ (kv & 7)) * 8);
          sc[mt] = __builtin_amdgcn_mfma_f32_16x16x32_bf16(kf, qf[kh], sc[mt], 0, 0, 0);
        }
      __builtin_amdgcn_s_setprio(0);

      const int kvb = kc * 64 + quad * 4;
      float mx = -INFINITY;
#pragma unroll
      for (int mt = 0; mt < 4; ++mt)
#pragma unroll
        for (int r = 0; r < 4; ++r) {
          float v = sc[mt][r];
          if (kvb + mt * 16 + r > q_g) v = -INFINITY;
          sc[mt][r] = v;
          mx = fmaxf(mx, v);
        }
      mx = fmaxf(mx, __shfl_xor(mx, 16));
      mx = fmaxf(mx, __shfl_xor(mx, 32));
      float mnew = fmaxf(m_i, mx);
      float alpha = exp2f((m_i - mnew) * C);
      m_i = mnew;
      float sum = 0.f;
#pragma unroll
      for (int mt = 0; mt < 4; ++mt)
#pragma unroll
        for (int r = 0; r < 4; ++r) {
          float p = exp2f((sc[mt][r] - m_i) * C);
          sc[mt][r] = p;
          sum += p;
        }
      sum += __shfl_xor(sum, 16);
      sum += __shfl_xor(sum, 32);
      l_i = l_i * alpha + sum;
#pragma unroll
      for (int mt = 0; mt < 4; ++mt)
#pragma unroll
        for (int r = 0; r < 4; ++r) o[mt][r] *= alpha;

#pragma unroll
      for (int mt = 0; mt < 4; ++mt) {
        unsigned int a0 = __float_as_uint(sc[mt][0]), a1 = __float_as_uint(sc[mt][1]);
        unsigned int a2 = __float_as_uint(sc[mt][2]), a3 = __float_as_uint(sc[mt][3]);
        uint2 pk;
        pk.x = (a0 >> 16) | (a1 & 0xffff0000u);
        pk.y = (a2 >> 16) | (a3 & 0xffff0000u);
        int grp = (mt * 4 + quad) ^ lrow;
        *(uint2*)(sPt + qloc * 64 + grp * 4) = pk;
      }

      __builtin_amdgcn_s_setprio(1);
#pragma unroll
      for (int kh = 0; kh < 2; ++kh) {
        int gbase = kh * 8 + quad * 2;
        uint2 b0 = *(const uint2*)(sPt + qloc * 64 + ((gbase) ^ lrow) * 4);
        uint2 b1 = *(const uint2*)(sPt + qloc * 64 + ((gbase + 1) ^ lrow) * 4);
        union { uint4 u; bf16_8 v; } bb;
        bb.u = make_uint4(b0.x, b0.y, b1.x, b1.y);
#pragma unroll
        for (int mt = 0; mt < 4; ++mt) {
          int d = mt * 16 + lrow;
          bf16_8 vf = *(const bf16_8*)(sVc + d * 64 + (((kh << 2) + quad) ^ (d & 7)) * 8);
          o[mt] = __builtin_amdgcn_mfma_f32_16x16x32_bf16(vf, bb.v, o[mt], 0, 0, 0);
        }
      }
      __builtin_amdgcn_s_setprio(0);
      cur ^= 1;
    }

    float inv = 1.f / l_i;
#pragma unroll
    for (int mt = 0; mt < 4; ++mt) {
      uint2 pk;
      pk.x = f2bf(o[mt][0] * inv) | ((unsigned int)f2bf(o[mt][1] * inv) << 16);
      pk.y = f2bf(o[mt][2] * inv) | ((unsigned int)f2bf(o[mt][3] * inv) << 16);
      int grp = (mt * 4 + quad) ^ lrow;
      *(uint2*)(sPt + qloc * 64 + grp * 4) = pk;
    }
    __syncthreads();
    {
      int row = tid >> 2, seg = tid & 3;
      uint2 w0 = *(const uint2*)(sPt + row * 64 + ((seg * 4 + 0) ^ (row & 15)) * 4);
      uint2 w1 = *(const uint2*)(sPt + row * 64 + ((seg * 4 + 1) ^ (row & 15)) * 4);
      uint2 w2 = *(const uint2*)(sPt + row * 64 + ((seg * 4 + 2) ^ (row & 15)) * 4);
      uint2 w3 = *(const uint2*)(sPt + row * 64 + ((seg * 4 + 3) ^ (row & 15)) * 4);
      size_t base = ((((size_t)b << 10) + qt * 64 + row) << 11) + h * 64 + seg * 16;
      *(uint4*)(Ow + base) = make_uint4(w0.x, w0.y, w1.x, w1.y);
      *(uint4*)(Ow + base + 8) = make_uint4(w2.x, w2.y, w3.x, w3.y);
    }
  }
}

// ---------------- kernel 3: output projection, fused bias -> f32 out --------
// 1D grid (512). XCD-rect swizzle: xcd=bid&7 owns an 8m x 8ty rectangle.
// Wo consumed directly as f32 (reg-cvt in B staging).
__global__ void __launch_bounds__(256)
out_gemm(const unsigned short* __restrict__ X, const float* __restrict__ Wo,
         const float* __restrict__ bo, float* __restrict__ out) {
  __shared__ unsigned short sA[128 * 64], sB[64 * 64];
  const int tid = threadIdx.x;
  const int bid = blockIdx.x;
  const int xcd = bid & 7, idx = bid >> 3;        // 64 blocks per XCD
  const int mt  = ((xcd & 1) << 3) + (idx >> 3);  // [0,16)
  const int ty  = ((xcd >> 1) << 3) + (idx & 7);  // [0,32)
  const int tileM = mt * 128, tileN = ty * 64;
  f32x4 acc[2][4] = {};
  gemm_core_n64(X + (size_t)tileM * 2048, Wo + (size_t)tileN * 2048, 2048, 2048,
                tid, sA, sB, acc);

  const int wave = tid >> 6, lane = tid & 63;
  const int wm = wave << 5;
  const int lrow = lane & 15, quad = lane >> 4;
#pragma unroll
  for (int j = 0; j < 4; ++j) {
    const int n = tileN + j * 16 + lrow;
    const float bj = bo[n];
#pragma unroll
    for (int i = 0; i < 2; ++i) {
      const int mbase = tileM + wm + i * 16 + quad * 4;
#pragma unroll
      for (int r = 0; r < 4; ++r)
        out[(size_t)(mbase + r) * 2048 + n] = acc[i][j][r] + bj;
    }
  }
}

extern "C" void kernel_launch(void* const* d_in, const int* in_sizes, int n_in,
                              void* d_out, int out_size, void* d_ws, size_t ws_size,
                              hipStream_t stream) {
  const float* x  = (const float*)d_in[0];
  const float* Wq = (const float*)d_in[2];
  const float* bq = (const float*)d_in[3];
  const float* Wk = (const float*)d_in[4];
  const float* bk = (const float*)d_in[5];
  const float* Wv = (const float*)d_in[6];
  const float* bv = (const float*)d_in[7];
  const float* Wo = (const float*)d_in[8];
  const float* bo = (const float*)d_in[9];

  unsigned short* xbf  = (unsigned short*)d_ws;                  // 4,194,304 el
  unsigned short* qws  = xbf  + (size_t)4194304;                 // [2,32,1024,64]
  unsigned short* kws  = qws  + (size_t)2 * 32 * 1024 * 64;      // [2,8,1024,64]
  unsigned short* vws  = kws  + (size_t)2 * 8 * 1024 * 64;       // [2,8,64,1024]
  unsigned short* aws  = vws  + (size_t)2 * 8 * 1024 * 64;       // [2,1024,2048]
  float* out = (float*)d_out;

  hipLaunchKernelGGL(cvt_kernel, dim3(4096), dim3(256), 0, stream, x, xbf);
  hipLaunchKernelGGL(qkv_gemm, dim3(768), dim3(256), 0, stream,
                     xbf, Wq, Wk, Wv, bq, bk, bv, qws, kws, vws);
  hipLaunchKernelGGL(attn_kernel, dim3(8, 32, 2), dim3(256), 0, stream,
                     qws, kws, vws, aws);
  hipLaunchKernelGGL(out_gemm, dim3(512), dim3(256), 0, stream,
                     aws, Wo, bo, out);
}

// Round 8
// 201.749 us; speedup vs baseline: 1.1086x; 1.1086x over previous
//
#include <hip/hip_runtime.h>
#include <stdint.h>

// GQA fused forward: B=2, S=1024, HIDDEN=2048, H=32, G=8, D=64, causal.
// I/O float32; internal bf16 MFMA. Mask input ignored (causal from indices).
//
// Pipeline (round 8: round-6 base + double-buffered GEMM staging):
//   0) cvt:       f32 -> bf16 copies of x, Wq, Wk, Wv, Wo
//   1) qkv_gemm:  128x64 tiles, 768 blocks (3/CU), full K=2048, fused bias+
//                 scatter. Double-buffered LDS staging (1 barrier/K-step,
//                 next tile's global_load_lds issued before MFMA).
//                 XCD-rect swizzle: each XCD owns 8m x 12ty.
//   2) attn:      S^T-form flash attention, PAIRED q-tiles {x,15-x} per block,
//                 Q direct from global, double-buffered K/V staging + setprio.
//   3) out_gemm:  same dbuf core, 512 blocks (2/CU), fused bias -> f32 out.
//                 XCD-rect swizzle: each XCD owns 8m x 8ty.
//
// NOTE (round-1 post-mortem): device-scope __threadfence() per block for a
// last-block split-K fixup compiles to buffer_wbl2/buffer_inv (full L2
// writeback+invalidate per XCD). Never fuse cross-block reductions via
// atomics+fences here (38us -> 150us).
//
// NOTE (round-4 post-mortem): un-pairing attn into 1024 one-q-tile blocks
// (4/CU) REGRESSED 35->50us (staging-queue contention + tail decay). Paired
// uniform blocks at 2/CU are faster. Do not un-pair.
//
// NOTE (round-6 post-mortem): XCD-rect swizzle was NEUTRAL -- GEMMs are
// staging-latency-bound, not HBM-BW-bound. Kept (harmless).
//
// NOTE (round-7 post-mortem): fusing weight f32->bf16 into GEMM B-staging
// REGRESSED 203->224 (qkv 58us, MfmaUtil 17%): reg-staging doubles B bytes,
// loses global_load_lds, and the loads still drain at the wave's next
// barrier with only 16 MFMAs to hide under. Keep the standalone cvt pass;
// weights must reach the GEMMs as bf16 staged via global_load_lds.

typedef __bf16 bf16_8 __attribute__((ext_vector_type(8)));
typedef float f32x4 __attribute__((ext_vector_type(4)));

__device__ __forceinline__ unsigned short f2bf(float f) {
  union { float f; unsigned int i; } c; c.f = f;
  unsigned int u = c.i;
  return (unsigned short)((u + 0x7fffu + ((u >> 16) & 1u)) >> 16);
}

__device__ __forceinline__ void gl2lds16(const void* g, void* l) {
  __builtin_amdgcn_global_load_lds(
      (const __attribute__((address_space(1))) void*)g,
      (__attribute__((address_space(3))) void*)l, 16, 0, 0);
}

// Stage ROWS x 64 bf16 tile (leading dim ldg) into LDS; per-row XOR swizzle of
// 8-elem groups: LDS[r][lg] = G[r][lg ^ (r&7)]. 256 threads.
template <int ROWS>
__device__ __forceinline__ void stage_tile(const unsigned short* g, int ldg,
                                           unsigned short* lds, int tid) {
#pragma unroll
  for (int i = 0; i < ROWS * 8 / 256; ++i) {
    int c = tid + i * 256;
    int r = c >> 3;
    int grp = (c & 7) ^ (r & 7);
    gl2lds16(g + (size_t)r * ldg + grp * 8, lds + c * 8);
  }
}

// Core 128x64 GEMM tile: Y = X[128,K] @ W[64,K]^T (leading dim ld).
// 4 waves, each owns a 32x64 output stripe: acc[2][4] of 16x16 frags.
// DOUBLE-BUFFERED: one barrier per K-step; stage(k+1) issued before MFMA(k)
// so the global_load_lds latency drains a full compute-phase after issue
// (same schedule as attn's K/V staging, validated r0->r2).
// sA: 2 x 128x64, sB: 2 x 64x64 (48 KB total).
__device__ __forceinline__ void gemm_core_n64(const unsigned short* Xt,
                                              const unsigned short* Wt,
                                              int kiter, int ld, int tid,
                                              unsigned short* sA,
                                              unsigned short* sB,
                                              f32x4 acc[2][4]) {
  const int wave = tid >> 6, lane = tid & 63;
  const int wm = wave << 5;
  const int lrow = lane & 15, quad = lane >> 4;
  stage_tile<128>(Xt, ld, sA, tid);
  stage_tile<64>(Wt, ld, sB, tid);
  int cur = 0;
  for (int k0 = 0; k0 < kiter; k0 += 64) {
    __syncthreads();  // staging(buf[cur]) drained; buf[cur^1] reads done
    if (k0 + 64 < kiter) {
      stage_tile<128>(Xt + k0 + 64, ld, sA + ((cur ^ 1) << 13), tid);
      stage_tile<64>(Wt + k0 + 64, ld, sB + ((cur ^ 1) << 12), tid);
    }
    const unsigned short* A = sA + (cur << 13);
    const unsigned short* Bt = sB + (cur << 12);
#pragma unroll
    for (int ks = 0; ks < 2; ++ks) {
      bf16_8 af[2], bw[4];
#pragma unroll
      for (int i = 0; i < 2; ++i) {
        int ra = wm + i * 16 + lrow;
        af[i] = *(const bf16_8*)(A + ra * 64 + (((ks << 2) + quad) ^ (ra & 7)) * 8);
      }
#pragma unroll
      for (int j = 0; j < 4; ++j) {
        int rb = j * 16 + lrow;
        bw[j] = *(const bf16_8*)(Bt + rb * 64 + (((ks << 2) + quad) ^ (rb & 7)) * 8);
      }
#pragma unroll
      for (int i = 0; i < 2; ++i)
#pragma unroll
        for (int j = 0; j < 4; ++j)
          acc[i][j] = __builtin_amdgcn_mfma_f32_16x16x32_bf16(af[i], bw[j],
                                                              acc[i][j], 0, 0, 0);
    }
    cur ^= 1;
  }
}

// ---------------- kernel 0: f32 -> bf16 conversion ----------------
__global__ void __launch_bounds__(256)
cvt_kernel(const float* __restrict__ s0, const float* __restrict__ s1,
           const float* __restrict__ s2, const float* __restrict__ s3,
           const float* __restrict__ s4,
           unsigned short* __restrict__ d0, unsigned short* __restrict__ d1,
           unsigned short* __restrict__ d2, unsigned short* __restrict__ d3,
           unsigned short* __restrict__ d4) {
  const float* src; unsigned short* dst; int n;
  switch (blockIdx.y) {
    case 0:  src = s0; dst = d0; n = 4194304; break;
    case 1:  src = s1; dst = d1; n = 4194304; break;
    case 2:  src = s2; dst = d2; n = 1048576; break;
    case 3:  src = s3; dst = d3; n = 1048576; break;
    default: src = s4; dst = d4; n = 4194304; break;
  }
  int idx = (blockIdx.x * 256 + threadIdx.x) * 4;
  if (idx >= n) return;
  float4 v = *(const float4*)(src + idx);
  ushort4 o;
  o.x = f2bf(v.x); o.y = f2bf(v.y); o.z = f2bf(v.z); o.w = f2bf(v.w);
  *(ushort4*)(dst + idx) = o;
}

// ---------------- kernel 1: QKV projection, fused bias+scatter -------------
// 1D grid (768). XCD-rect swizzle: xcd=bid&7 owns an 8m x 12ty rectangle.
// ty 0..31 -> Q head ty; 32..39 -> K group; 40..47 -> V group (n = ty*64).
__global__ void __launch_bounds__(256)
qkv_gemm(const unsigned short* __restrict__ X,
         const unsigned short* __restrict__ Wq,
         const unsigned short* __restrict__ Wk,
         const unsigned short* __restrict__ Wv,
         const float* __restrict__ bq, const float* __restrict__ bk,
         const float* __restrict__ bv,
         unsigned short* __restrict__ qws, unsigned short* __restrict__ kws,
         unsigned short* __restrict__ vws) {
  __shared__ unsigned short sA[2 * 128 * 64], sB[2 * 64 * 64];
  const int tid = threadIdx.x;
  const int bid = blockIdx.x;
  const int xcd = bid & 7, idx = bid >> 3;        // 96 blocks per XCD
  const int mt  = ((xcd & 1) << 3) + idx / 12;    // [0,16)
  const int ty  = (xcd >> 1) * 12 + idx % 12;     // [0,48)
  const int tileM = mt * 128;
  const unsigned short* W;
  const float* bias;
  if (ty < 32)      { W = Wq + (size_t)ty * 64 * 2048;        bias = bq + ty * 64; }
  else if (ty < 40) { W = Wk + (size_t)(ty - 32) * 64 * 2048; bias = bk + (ty - 32) * 64; }
  else              { W = Wv + (size_t)(ty - 40) * 64 * 2048; bias = bv + (ty - 40) * 64; }

  f32x4 acc[2][4] = {};
  gemm_core_n64(X + (size_t)tileM * 2048, W, 2048, 2048, tid, sA, sB, acc);

  const int wave = tid >> 6, lane = tid & 63;
  const int wm = wave << 5;
  const int lrow = lane & 15, quad = lane >> 4;

#pragma unroll
  for (int j = 0; j < 4; ++j) {
    const int dloc = j * 16 + lrow;          // 0..63: dim within this 64-slice
    const float bj = bias[dloc];
#pragma unroll
    for (int i = 0; i < 2; ++i) {
      const int mbase = tileM + wm + i * 16 + quad * 4;
      const int b = mbase >> 10;
      const int s = mbase & 1023;            // s, s+1, s+2, s+3 for r=0..3
      if (ty < 32) {
        unsigned short* p = qws + ((((size_t)b * 32 + ty) << 10) + s) * 64 + dloc;
#pragma unroll
        for (int r = 0; r < 4; ++r) p[r * 64] = f2bf(acc[i][j][r] + bj);
      } else if (ty < 40) {
        unsigned short* p = kws + ((((size_t)b * 8 + (ty - 32)) << 10) + s) * 64 + dloc;
#pragma unroll
        for (int r = 0; r < 4; ++r) p[r * 64] = f2bf(acc[i][j][r] + bj);
      } else {
        // vws[b, g, d, s] (transposed): r=0..3 are consecutive s -> pack 8B
        unsigned short* p = vws + ((((size_t)b * 8 + (ty - 40)) * 64 + dloc) << 10) + s;
        uint2 pk;
        pk.x = f2bf(acc[i][j][0] + bj) | ((unsigned int)f2bf(acc[i][j][1] + bj) << 16);
        pk.y = f2bf(acc[i][j][2] + bj) | ((unsigned int)f2bf(acc[i][j][3] + bj) << 16);
        *(uint2*)p = pk;
      }
    }
  }
}

// ---------------- kernel 2: causal flash attention (S^T form) ----------------
// grid (8, 32, 2): (pair, head, batch). Block handles q-tiles {x, 15-x}:
// uniform 17 kc-iters per block, XCD-balanced by construction. Q fragments
// loaded direct from global (no sQ; LDS 40KB). Double-buffered K/V staging:
// 1 barrier/iter, next tile staged before compute. setprio around MFMA.
__global__ void __launch_bounds__(256)
attn_kernel(const unsigned short* __restrict__ Qw, const unsigned short* __restrict__ Kw,
            const unsigned short* __restrict__ Vt, unsigned short* __restrict__ Ow) {
  __shared__ unsigned short sK[2][64 * 64], sVt[2][64 * 64], sPt[64 * 64];
  const int tid = threadIdx.x;
  const int pair = blockIdx.x, h = blockIdx.y, b = blockIdx.z;
  const int g = h >> 2;
  const unsigned short* Kb = Kw + (((size_t)b * 8 + g) << 16);  // [s][d]
  const unsigned short* Vb = Vt + (((size_t)b * 8 + g) << 16);  // [d][s], ld=1024
  const int wave = tid >> 6, lane = tid & 63;
  const int lrow = lane & 15, quad = lane >> 4;
  const int qloc = wave * 16 + lrow;
  const float C = 0.18033688f;  // 0.125 * log2(e)

#pragma unroll 1
  for (int t = 0; t < 2; ++t) {
    const int qt = t ? (15 - pair) : pair;
    __syncthreads();  // protect sK/sVt/sPt reuse across t iterations

    // Q fragments straight from global: Q[b,h, qt*64+qloc, (kh*4+quad)*8 ..+8]
    const unsigned short* Qrow =
        Qw + ((((size_t)b * 32 + h) << 10) + qt * 64 + qloc) * 64;
    bf16_8 qf[2];
#pragma unroll
    for (int kh = 0; kh < 2; ++kh)
      qf[kh] = *(const bf16_8*)(Qrow + ((kh << 2) + quad) * 8);

    stage_tile<64>(Kb, 64, sK[0], tid);
    stage_tile<64>(Vb, 1024, sVt[0], tid);
    __syncthreads();

    float m_i = -INFINITY, l_i = 0.f;
    f32x4 o[4] = {};
    const int q_g = qt * 64 + qloc;
    int cur = 0;

#pragma unroll 1
    for (int kc = 0; kc <= qt; ++kc) {
      if (kc) __syncthreads();  // staging of buf[cur] done; buf[cur^1] free
      if (kc < qt) {
        // issue next-tile staging BEFORE compute: latency hides under MFMA
        stage_tile<64>(Kb + (size_t)(kc + 1) * 64 * 64, 64, sK[cur ^ 1], tid);
        stage_tile<64>(Vb + (kc + 1) * 64, 1024, sVt[cur ^ 1], tid);
      }
      const unsigned short* sKc = sK[cur];
      const unsigned short* sVc = sVt[cur];

      f32x4 sc[4] = {};
      __builtin_amdgcn_s_setprio(1);
#pragma unroll
      for (int kh = 0; kh < 2; ++kh)
#pragma unroll
        for (int mt = 0; mt < 4; ++mt) {
          int kv = mt * 16 + lrow;
          bf16_8 kf = *(const bf16_8*)(sKc + kv * 64 + (((kh << 2) + quad) ^ (kv & 7)) * 8);
          sc[mt] = __builtin_amdgcn_mfma_f32_16x16x32_bf16(kf, qf[kh], sc[mt], 0, 0, 0);
        }
      __builtin_amdgcn_s_setprio(0);

      const int kvb = kc * 64 + quad * 4;
      float mx = -INFINITY;
#pragma unroll
      for (int mt = 0; mt < 4; ++mt)
#pragma unroll
        for (int r = 0; r < 4; ++r) {
          float v = sc[mt][r];
          if (kvb + mt * 16 + r > q_g) v = -INFINITY;
          sc[mt][r] = v;
          mx = fmaxf(mx, v);
        }
      mx = fmaxf(mx, __shfl_xor(mx, 16));
      mx = fmaxf(mx, __shfl_xor(mx, 32));
      float mnew = fmaxf(m_i, mx);
      float alpha = exp2f((m_i - mnew) * C);
      m_i = mnew;
      float sum = 0.f;
#pragma unroll
      for (int mt = 0; mt < 4; ++mt)
#pragma unroll
        for (int r = 0; r < 4; ++r) {
          float p = exp2f((sc[mt][r] - m_i) * C);
          sc[mt][r] = p;
          sum += p;
        }
      sum += __shfl_xor(sum, 16);
      sum += __shfl_xor(sum, 32);
      l_i = l_i * alpha + sum;
#pragma unroll
      for (int mt = 0; mt < 4; ++mt)
#pragma unroll
        for (int r = 0; r < 4; ++r) o[mt][r] *= alpha;

#pragma unroll
      for (int mt = 0; mt < 4; ++mt) {
        unsigned int a0 = __float_as_uint(sc[mt][0]), a1 = __float_as_uint(sc[mt][1]);
        unsigned int a2 = __float_as_uint(sc[mt][2]), a3 = __float_as_uint(sc[mt][3]);
        uint2 pk;
        pk.x = (a0 >> 16) | (a1 & 0xffff0000u);
        pk.y = (a2 >> 16) | (a3 & 0xffff0000u);
        int grp = (mt * 4 + quad) ^ lrow;
        *(uint2*)(sPt + qloc * 64 + grp * 4) = pk;
      }

      __builtin_amdgcn_s_setprio(1);
#pragma unroll
      for (int kh = 0; kh < 2; ++kh) {
        int gbase = kh * 8 + quad * 2;
        uint2 b0 = *(const uint2*)(sPt + qloc * 64 + ((gbase) ^ lrow) * 4);
        uint2 b1 = *(const uint2*)(sPt + qloc * 64 + ((gbase + 1) ^ lrow) * 4);
        union { uint4 u; bf16_8 v; } bb;
        bb.u = make_uint4(b0.x, b0.y, b1.x, b1.y);
#pragma unroll
        for (int mt = 0; mt < 4; ++mt) {
          int d = mt * 16 + lrow;
          bf16_8 vf = *(const bf16_8*)(sVc + d * 64 + (((kh << 2) + quad) ^ (d & 7)) * 8);
          o[mt] = __builtin_amdgcn_mfma_f32_16x16x32_bf16(vf, bb.v, o[mt], 0, 0, 0);
        }
      }
      __builtin_amdgcn_s_setprio(0);
      cur ^= 1;
    }

    float inv = 1.f / l_i;
#pragma unroll
    for (int mt = 0; mt < 4; ++mt) {
      uint2 pk;
      pk.x = f2bf(o[mt][0] * inv) | ((unsigned int)f2bf(o[mt][1] * inv) << 16);
      pk.y = f2bf(o[mt][2] * inv) | ((unsigned int)f2bf(o[mt][3] * inv) << 16);
      int grp = (mt * 4 + quad) ^ lrow;
      *(uint2*)(sPt + qloc * 64 + grp * 4) = pk;
    }
    __syncthreads();
    {
      int row = tid >> 2, seg = tid & 3;
      uint2 w0 = *(const uint2*)(sPt + row * 64 + ((seg * 4 + 0) ^ (row & 15)) * 4);
      uint2 w1 = *(const uint2*)(sPt + row * 64 + ((seg * 4 + 1) ^ (row & 15)) * 4);
      uint2 w2 = *(const uint2*)(sPt + row * 64 + ((seg * 4 + 2) ^ (row & 15)) * 4);
      uint2 w3 = *(const uint2*)(sPt + row * 64 + ((seg * 4 + 3) ^ (row & 15)) * 4);
      size_t base = ((((size_t)b << 10) + qt * 64 + row) << 11) + h * 64 + seg * 16;
      *(uint4*)(Ow + base) = make_uint4(w0.x, w0.y, w1.x, w1.y);
      *(uint4*)(Ow + base + 8) = make_uint4(w2.x, w2.y, w3.x, w3.y);
    }
  }
}

// ---------------- kernel 3: output projection, fused bias -> f32 out --------
// 1D grid (512). XCD-rect swizzle: xcd=bid&7 owns an 8m x 8ty rectangle.
__global__ void __launch_bounds__(256)
out_gemm(const unsigned short* __restrict__ X, const unsigned short* __restrict__ Wo,
         const float* __restrict__ bo, float* __restrict__ out) {
  __shared__ unsigned short sA[2 * 128 * 64], sB[2 * 64 * 64];
  const int tid = threadIdx.x;
  const int bid = blockIdx.x;
  const int xcd = bid & 7, idx = bid >> 3;        // 64 blocks per XCD
  const int mt  = ((xcd & 1) << 3) + (idx >> 3);  // [0,16)
  const int ty  = ((xcd >> 1) << 3) + (idx & 7);  // [0,32)
  const int tileM = mt * 128, tileN = ty * 64;
  f32x4 acc[2][4] = {};
  gemm_core_n64(X + (size_t)tileM * 2048, Wo + (size_t)tileN * 2048, 2048, 2048,
                tid, sA, sB, acc);

  const int wave = tid >> 6, lane = tid & 63;
  const int wm = wave << 5;
  const int lrow = lane & 15, quad = lane >> 4;
#pragma unroll
  for (int j = 0; j < 4; ++j) {
    const int n = tileN + j * 16 + lrow;
    const float bj = bo[n];
#pragma unroll
    for (int i = 0; i < 2; ++i) {
      const int mbase = tileM + wm + i * 16 + quad * 4;
#pragma unroll
      for (int r = 0; r < 4; ++r)
        out[(size_t)(mbase + r) * 2048 + n] = acc[i][j][r] + bj;
    }
  }
}

extern "C" void kernel_launch(void* const* d_in, const int* in_sizes, int n_in,
                              void* d_out, int out_size, void* d_ws, size_t ws_size,
                              hipStream_t stream) {
  const float* x  = (const float*)d_in[0];
  const float* Wq = (const float*)d_in[2];
  const float* bq = (const float*)d_in[3];
  const float* Wk = (const float*)d_in[4];
  const float* bk = (const float*)d_in[5];
  const float* Wv = (const float*)d_in[6];
  const float* bv = (const float*)d_in[7];
  const float* Wo = (const float*)d_in[8];
  const float* bo = (const float*)d_in[9];

  unsigned short* xbf  = (unsigned short*)d_ws;                  // 4,194,304 el
  unsigned short* wqbf = xbf  + (size_t)4194304;
  unsigned short* wkbf = wqbf + (size_t)4194304;
  unsigned short* wvbf = wkbf + (size_t)1048576;
  unsigned short* wobf = wvbf + (size_t)1048576;
  unsigned short* qws  = wobf + (size_t)4194304;                 // [2,32,1024,64]
  unsigned short* kws  = qws  + (size_t)2 * 32 * 1024 * 64;      // [2,8,1024,64]
  unsigned short* vws  = kws  + (size_t)2 * 8 * 1024 * 64;       // [2,8,64,1024]
  unsigned short* aws  = vws  + (size_t)2 * 8 * 1024 * 64;       // [2,1024,2048]
  float* out = (float*)d_out;

  hipLaunchKernelGGL(cvt_kernel, dim3(4096, 5), dim3(256), 0, stream,
                     x, Wq, Wk, Wv, Wo, xbf, wqbf, wkbf, wvbf, wobf);
  hipLaunchKernelGGL(qkv_gemm, dim3(768), dim3(256), 0, stream,
                     xbf, wqbf, wkbf, wvbf, bq, bk, bv, qws, kws, vws);
  hipLaunchKernelGGL(attn_kernel, dim3(8, 32, 2), dim3(256), 0, stream,
                     qws, kws, vws, aws);
  hipLaunchKernelGGL(out_gemm, dim3(512), dim3(256), 0, stream,
                     aws, wobf, bo, out);
}